// Round 9
// baseline (5228.624 us; speedup 1.0000x reference)
//
#include <hip/hip_runtime.h>
#include <hip/hip_bf16.h>
#include <math.h>

// Problem dims (fixed by the reference)
#define RB 64
#define RS 512
#define RE 1024
#define RH 1024
#define BSH ((size_t)RB * RS * RH)

// ---------------------------------------------------------------------------
// Round-9 structure: LATENCY HIDING BY CHAIN MULTIPLEXING.
// The 4 row groups (16 batch rows each) are independent recurrences. 64
// blocks, each owns cols [16cg,16cg+16) for ALL 64 rows = 4 chains. Per slot
// s, a block: polls ONCE (all 64 blocks' flags >= s+1), then processes the 4
// chains back-to-back, with chain i+1's h3 fragment loads issued before chain
// i's MFMA/reduce (xA/xB ping-pong, static indices). U^T fragments are shared
// by all 4 chains (same columns) -> register cost unchanged. One flag store
// per slot covers all 4 patches. When slot compute (~1.5-2us) exceeds the
// publish-visibility latency, polls pass on round 1 and the cross-die latency
// leaves the critical path entirely (R5-R8 showed it was ~3.7us/step there).
//
// Sync protocol: VERBATIM round-6 flag induction. flag[cg] = g means block cg
// finished slot g-2 and its h3_{g-1} agent-scope publishes are visible at L3
// (flag stored after a __syncthreads that drains vmcnt). Passing the poll for
// g also proves every block finished its slot g-2 READS, so the h3 ping-pong
// (buffer s&1) can never overwrite unread data.
// Workspace: hbuf 256 KB + flags (proven footprint).
// ---------------------------------------------------------------------------
#define NBLK_SCAN 64

typedef __attribute__((ext_vector_type(8))) __bf16 bf16x8;
typedef __attribute__((ext_vector_type(4))) float  f32x4;

__device__ __forceinline__ bf16x8 cvt8(f32x4 a, f32x4 b) {
    bf16x8 r;
    r[0] = (__bf16)a[0]; r[1] = (__bf16)a[1];
    r[2] = (__bf16)a[2]; r[3] = (__bf16)a[3];
    r[4] = (__bf16)b[0]; r[5] = (__bf16)b[1];
    r[6] = (__bf16)b[2]; r[7] = (__bf16)b[3];
    return r;
}

// L2-bypassing (agent-scope => L3 coherent point) accessors for cross-XCD data.
__device__ __forceinline__ bf16x8 ld_frag_agent(const unsigned long long* p) {
    union { unsigned long long u[2]; bf16x8 v; } r;
    r.u[0] = __hip_atomic_load(p,     __ATOMIC_RELAXED, __HIP_MEMORY_SCOPE_AGENT);
    r.u[1] = __hip_atomic_load(p + 1, __ATOMIC_RELAXED, __HIP_MEMORY_SCOPE_AGENT);
    return r.v;
}
__device__ __forceinline__ void st_bf16_agent(__bf16* p, float v) {
    union { __bf16 b; unsigned short s; } u;
    u.b = (__bf16)v;
    __hip_atomic_store(reinterpret_cast<unsigned short*>(p), u.s,
                       __ATOMIC_RELAXED, __HIP_MEMORY_SCOPE_AGENT);
}

// ---------------------------------------------------------------------------
// Phase 0: zero the progress flags (d_ws is re-poisoned each call).
// ---------------------------------------------------------------------------
__global__ void init_flags_k(unsigned* flags) {
    if (threadIdx.x < 256) flags[threadIdx.x] = 0u;
}

// ---------------------------------------------------------------------------
// Phase 1: wx[m,h] = sum_e x[m,e]*W_w[h,e] + W_b[h]
// 128x128 tile, BK=64, reg-staged fp32->bf16 into padded LDS, 2x2 wave grid,
// 4x4 16x16x32 MFMA fragments per wave. (unchanged — known good)
// ---------------------------------------------------------------------------
#define WBK  64
#define LDST 72   // 64 + 8 pad bf16 elems; 144 B row stride (16B-aligned)

__global__ __launch_bounds__(256) void wx_gemm(
    const float* __restrict__ X,
    const float* __restrict__ Ww,
    const float* __restrict__ Wb,
    float* __restrict__ Out)
{
    __shared__ __align__(16) __bf16 As[128 * LDST];
    __shared__ __align__(16) __bf16 Bs[128 * LDST];

    const int tid  = threadIdx.x;
    const int lane = tid & 63;
    const int wave = tid >> 6;
    const int m0   = blockIdx.y * 128;
    const int n0   = blockIdx.x * 128;
    const int wm   = (wave >> 1) * 64;
    const int wn   = (wave & 1) * 64;

    const int sk   = (tid & 7) * 8;
    const int srow = tid >> 3;

    f32x4 acc[4][4];
#pragma unroll
    for (int i = 0; i < 4; ++i)
#pragma unroll
        for (int j = 0; j < 4; ++j) acc[i][j] = (f32x4){0.f, 0.f, 0.f, 0.f};

    for (int kc = 0; kc < RE; kc += WBK) {
#pragma unroll
        for (int rr = 0; rr < 128; rr += 32) {
            const float* xp = X + (size_t)(m0 + srow + rr) * RE + kc + sk;
            *reinterpret_cast<bf16x8*>(&As[(srow + rr) * LDST + sk]) =
                cvt8(*reinterpret_cast<const f32x4*>(xp),
                     *reinterpret_cast<const f32x4*>(xp + 4));
            const float* wp = Ww + (size_t)(n0 + srow + rr) * RE + kc + sk;
            *reinterpret_cast<bf16x8*>(&Bs[(srow + rr) * LDST + sk]) =
                cvt8(*reinterpret_cast<const f32x4*>(wp),
                     *reinterpret_cast<const f32x4*>(wp + 4));
        }
        __syncthreads();

#pragma unroll
        for (int ks = 0; ks < 2; ++ks) {
            bf16x8 af[4], bfr[4];
#pragma unroll
            for (int i = 0; i < 4; ++i) {
                af[i]  = *reinterpret_cast<const bf16x8*>(
                    &As[(wm + i * 16 + (lane & 15)) * LDST + ks * 32 + (lane >> 4) * 8]);
                bfr[i] = *reinterpret_cast<const bf16x8*>(
                    &Bs[(wn + i * 16 + (lane & 15)) * LDST + ks * 32 + (lane >> 4) * 8]);
            }
#pragma unroll
            for (int i = 0; i < 4; ++i)
#pragma unroll
                for (int j = 0; j < 4; ++j)
                    acc[i][j] = __builtin_amdgcn_mfma_f32_16x16x32_bf16(
                        af[i], bfr[j], acc[i][j], 0, 0, 0);
        }
        __syncthreads();
    }

    const int col = lane & 15, rbase = (lane >> 4) * 4;
#pragma unroll
    for (int j = 0; j < 4; ++j) {
        const int n = n0 + wn + j * 16 + col;
        const float bias = Wb[n];
#pragma unroll
        for (int i = 0; i < 4; ++i) {
#pragma unroll
            for (int r = 0; r < 4; ++r) {
                const int m = m0 + wm + i * 16 + rbase + r;
                Out[(size_t)m * RH + n] = acc[i][j][r] + bias;
            }
        }
    }
}

// ---------------------------------------------------------------------------
// Phase 2: persistent scan, 64 blocks x 256 thr, 4 chains per block.
// ---------------------------------------------------------------------------

// One chain's MFMA + LDS reduce + publish. X = bf16x8[8] fragment buffer.
#define CHAIN_COMPUTE(RG, X)                                                    \
    {                                                                           \
        f32x4 ac0 = (f32x4){0.f, 0.f, 0.f, 0.f};                                \
        f32x4 ac1 = ac0, ac2 = ac0, ac3 = ac0;                                  \
        ac0 = __builtin_amdgcn_mfma_f32_16x16x32_bf16(X[0], ufr[0], ac0, 0,0,0);\
        ac1 = __builtin_amdgcn_mfma_f32_16x16x32_bf16(X[1], ufr[1], ac1, 0,0,0);\
        ac2 = __builtin_amdgcn_mfma_f32_16x16x32_bf16(X[2], ufr[2], ac2, 0,0,0);\
        ac3 = __builtin_amdgcn_mfma_f32_16x16x32_bf16(X[3], ufr[3], ac3, 0,0,0);\
        ac0 = __builtin_amdgcn_mfma_f32_16x16x32_bf16(X[4], ufr[4], ac0, 0,0,0);\
        ac1 = __builtin_amdgcn_mfma_f32_16x16x32_bf16(X[5], ufr[5], ac1, 0,0,0);\
        ac2 = __builtin_amdgcn_mfma_f32_16x16x32_bf16(X[6], ufr[6], ac2, 0,0,0);\
        ac3 = __builtin_amdgcn_mfma_f32_16x16x32_bf16(X[7], ufr[7], ac3, 0,0,0);\
        const f32x4 accv = (ac0 + ac1) + (ac2 + ac3);                           \
        float* rb = red[(RG) & 1];                                              \
        _Pragma("unroll")                                                       \
        for (int r = 0; r < 4; ++r)                                             \
            rb[wave * 256 + ((lane >> 4) * 4 + r) * 16 + (lane & 15)] = accv[r];\
        __syncthreads();                                                        \
        const float v = rb[tid] + rb[256 + tid] + rb[512 + tid] + rb[768 + tid] \
                      + ubs[tid & 15];                                          \
        vout[RG] = v;                                                           \
        if (s < RS - 1)                                                         \
            st_bf16_agent(nxt + ((RG) * 16 + er) * RH + ecol,                   \
                          tanhf(wn[RG] + v));                                   \
    }

__global__ __launch_bounds__(256, 1) void rnn_scan4(
    const float* __restrict__ Uw,
    const float* __restrict__ Ub,
    float* Out,               // [B*S*H] (wx -> result1) then [B*H] t_final
    __bf16* hbuf,             // 2 * B * H bf16, double-buffered h3 (256 KB)
    unsigned* flags)          // 64 progress flags (one per block)
{
    __shared__ float red[2][4 * 256];
    __shared__ float ubs[16];

    const int tid  = threadIdx.x;
    const int lane = tid & 63;
    const int wave = tid >> 6;           // K-slice index 0..3 (K=256 each)
    const int cg   = blockIdx.x;         // column group 0..63
    const int col0 = cg * 16;

    // register-resident U^T slice, SHARED by all 4 chains:
    // n = lane&15 (col), k = 256*wave + 32*j + (lane>>4)*8
    bf16x8 ufr[8];
    {
        const float* up = Uw + (size_t)(col0 + (lane & 15)) * RH
                        + 256 * wave + ((lane >> 4) * 8);
#pragma unroll
        for (int j = 0; j < 8; ++j)
            ufr[j] = cvt8(*reinterpret_cast<const f32x4*>(up + j * 32),
                          *reinterpret_cast<const f32x4*>(up + j * 32 + 4));
    }
    if (tid < 16) ubs[tid] = Ub[col0 + tid];

    // epilogue mapping: thread -> one element per chain's 16x16 patch
    const int er   = tid >> 4;           // row within group 0..15
    const int ecol = col0 + (tid & 15);

    // --- h3_0 = tanh(wx[:,0,patch]) for all 4 chains, + wx(1) prefetch ---
    float wn[4];
#pragma unroll
    for (int rg = 0; rg < 4; ++rg) {
        const int erow = rg * 16 + er;
        const float w = Out[(size_t)erow * RS * RH + ecol];
        st_bf16_agent(hbuf + erow * RH + ecol, tanhf(w));
        wn[rg] = Out[(size_t)erow * RS * RH + (size_t)1 * RH + ecol];
    }
    __syncthreads();                         // drains h3_0 stores (vmcnt)
    if (tid == 0)
        __hip_atomic_store(&flags[cg], 1u,
                           __ATOMIC_RELAXED, __HIP_MEMORY_SCOPE_AGENT);

    const int arow_in = lane & 15;                 // row within chain group
    const int kbase   = 256 * wave + (lane >> 4) * 8;

    for (int s = 0; s < RS; ++s) {
        const __bf16* cur = hbuf + (size_t)(s & 1) * (RB * RH);
        __bf16*       nxt = hbuf + (size_t)((s + 1) & 1) * (RB * RH);

        // --- ONE poll per slot: all 64 blocks' flags >= s+1 ---
        const unsigned tgt = (unsigned)(s + 1);
        while (true) {
            const unsigned f = __hip_atomic_load(&flags[lane],
                                                 __ATOMIC_RELAXED,
                                                 __HIP_MEMORY_SCOPE_AGENT);
            if (__all(f >= tgt)) break;
            __builtin_amdgcn_s_sleep(1);
        }
        __builtin_amdgcn_sched_barrier(0);
        asm volatile("" ::: "memory");

        // per-chain A-frag base pointers (u64 view; frag f at +f*8 u64)
        const unsigned long long* cp0 = reinterpret_cast<const unsigned long long*>(cur)
            + ((size_t)(0 * 16 + arow_in) * RH + kbase) / 4;
        const unsigned long long* cp1 = reinterpret_cast<const unsigned long long*>(cur)
            + ((size_t)(1 * 16 + arow_in) * RH + kbase) / 4;
        const unsigned long long* cp2 = reinterpret_cast<const unsigned long long*>(cur)
            + ((size_t)(2 * 16 + arow_in) * RH + kbase) / 4;
        const unsigned long long* cp3 = reinterpret_cast<const unsigned long long*>(cur)
            + ((size_t)(3 * 16 + arow_in) * RH + kbase) / 4;

        float vout[4];
        bf16x8 xA[8], xB[8];

        // software pipeline: chain i+1 loads issued before chain i compute
#pragma unroll
        for (int f = 0; f < 8; ++f) xA[f] = ld_frag_agent(cp0 + f * 8);
#pragma unroll
        for (int f = 0; f < 8; ++f) xB[f] = ld_frag_agent(cp1 + f * 8);
        CHAIN_COMPUTE(0, xA)
#pragma unroll
        for (int f = 0; f < 8; ++f) xA[f] = ld_frag_agent(cp2 + f * 8);
        CHAIN_COMPUTE(1, xB)
#pragma unroll
        for (int f = 0; f < 8; ++f) xB[f] = ld_frag_agent(cp3 + f * 8);
        CHAIN_COMPUTE(2, xA)
        CHAIN_COMPUTE(3, xB)

        if (s < RS - 1) {
            __syncthreads();                 // drains chain-3 publish (vmcnt)
            if (tid == 0)
                __hip_atomic_store(&flags[cg], (unsigned)(s + 2),
                                   __ATOMIC_RELAXED, __HIP_MEMORY_SCOPE_AGENT);
        }

        // deferred Out stores (overlap next slot's poll) + next wn prefetch
#pragma unroll
        for (int rg = 0; rg < 4; ++rg) {
            const int erow = rg * 16 + er;
            Out[(size_t)erow * RS * RH + (size_t)s * RH + ecol] = vout[rg];
            if (s == RS - 1)
                Out[BSH + (size_t)erow * RH + ecol] = vout[rg];   // t_final
            else if (s < RS - 2)
                wn[rg] = Out[(size_t)erow * RS * RH + (size_t)(s + 2) * RH + ecol];
        }
    }
}

// ---------------------------------------------------------------------------
extern "C" void kernel_launch(void* const* d_in, const int* in_sizes, int n_in,
                              void* d_out, int out_size, void* d_ws, size_t ws_size,
                              hipStream_t stream)
{
    const float* X  = (const float*)d_in[0];   // [B,S,E] fp32
    const float* Ww = (const float*)d_in[1];   // [H,E]   fp32
    const float* Wb = (const float*)d_in[2];   // [H]     fp32
    const float* Uw = (const float*)d_in[3];   // [H,H]   fp32
    const float* Ub = (const float*)d_in[4];   // [H]     fp32
    float* Out = (float*)d_out;                // [B*S*H] result1 + [B*H] t_final

    __bf16* hbuf = (__bf16*)d_ws;              // 2*B*H bf16 = 256 KB
    unsigned* flags = (unsigned*)((char*)d_ws + (size_t)2 * RB * RH * sizeof(__bf16));

    hipLaunchKernelGGL(init_flags_k, dim3(1), dim3(256), 0, stream, flags);
    hipLaunchKernelGGL(wx_gemm, dim3(RH / 128, (RB * RS) / 128), dim3(256), 0, stream,
                       X, Ww, Wb, Out);
    hipLaunchKernelGGL(rnn_scan4, dim3(NBLK_SCAN), dim3(256), 0, stream,
                       Uw, Ub, Out, hbuf, flags);
}